// Round 15
// baseline (419.933 us; speedup 1.0000x reference)
//
#include <hip/hip_runtime.h>
#include <hip/hip_bf16.h>

typedef unsigned short ushort_t;
typedef __bf16 bf16x8 __attribute__((ext_vector_type(8)));
typedef float f32x4 __attribute__((ext_vector_type(4)));

#define N_TOK 2048
#define DH    1024
#define FF    512
#define SFF   2816
#define NE    16
#define CAP   1024   // per-expert slot capacity (actual max ~330 with this router input)

#define GBM 64   // gateup M-tile
#define DBM 64   // down M-tile
#define BN 64
#define BK 64
#define LDK 72   // 64 + 8 pad (ushorts)

// manual RNE bf16 convert (scalar, epilogue use)
__device__ __forceinline__ ushort_t f2bf(float f) {
  unsigned int x = __float_as_uint(f);
  unsigned int lsb = (x >> 16) & 1u;
  x += 0x7fffu + lsb;            // RNE; finite inputs
  return (ushort_t)(x >> 16);
}
__device__ __forceinline__ float bf2f(ushort_t u) {
  union { unsigned int i; float f; } v; v.i = ((unsigned int)u) << 16; return v.f;
}
// packed HW convert: 2 fp32 -> 2 bf16 (RNE), 1 VALU op (r14: -26 us on gateup)
__device__ __forceinline__ unsigned int cvtpk(float lo, float hi) {
  unsigned int r;
  asm("v_cvt_pk_bf16_f32 %0, %1, %2" : "=v"(r) : "v"(lo), "v"(hi));
  return r;
}
__device__ __forceinline__ uint4 cvt8v(const float4 a, const float4 b) {
  uint4 v;
  v.x = cvtpk(a.x, a.y); v.y = cvtpk(a.z, a.w);
  v.z = cvtpk(b.x, b.y); v.w = cvtpk(b.z, b.w);
  return v;
}
__device__ __forceinline__ uint4 ld_cvt8(const float* __restrict__ p) {
  float4 a = *(const float4*)p;
  float4 b = *(const float4*)(p + 4);
  return cvt8v(a, b);
}

// ---------------- router + slot assignment (scatter eliminated via CAP layout) ----------------
__global__ void router_kernel(const float* __restrict__ X, const float* __restrict__ GW,
                              const float* __restrict__ SGW,
                              int* __restrict__ toks, int* __restrict__ slot_of,
                              float* __restrict__ wtk, float* __restrict__ sgate,
                              int* __restrict__ cnt) {
  int wave = threadIdx.x >> 6, lane = threadIdx.x & 63;
  int n = blockIdx.x * 4 + wave;
  const float* x = X + (size_t)n * DH;
  int e = lane & 15, s = lane >> 4;
  const float* gw = GW + (size_t)e * DH;
  float lg = 0.f;
  #pragma unroll
  for (int i = 0; i < 64; ++i) {
    int d = s * 256 + i * 4;
    float4 xv = *(const float4*)(x + d);
    float4 gv = *(const float4*)(gw + d);
    lg += xv.x * gv.x + xv.y * gv.y + xv.z * gv.z + xv.w * gv.w;
  }
  lg += __shfl_down(lg, 32);
  lg += __shfl_down(lg, 16);          // lanes 0..15 hold logits[e]

  float gd = 0.f;
  #pragma unroll
  for (int i = 0; i < 4; ++i) {
    int d = lane * 16 + i * 4;
    float4 xv = *(const float4*)(x + d);
    float4 gv = *(const float4*)(SGW + d);
    gd += xv.x * gv.x + xv.y * gv.y + xv.z * gv.z + xv.w * gv.w;
  }
  #pragma unroll
  for (int off = 32; off >= 1; off >>= 1) gd += __shfl_down(gd, off);

  float l[16];
  #pragma unroll
  for (int i = 0; i < 16; ++i) l[i] = __shfl(lg, i);

  if (lane == 0) {
    int i1 = 0; float v1 = l[0];
    #pragma unroll
    for (int i = 1; i < 16; ++i) if (l[i] > v1) { v1 = l[i]; i1 = i; }
    int i2 = -1; float v2 = -1e30f;
    #pragma unroll
    for (int i = 0; i < 16; ++i) { if (i == i1) continue; if (l[i] > v2) { v2 = l[i]; i2 = i; } }
    float p2 = __expf(v2 - v1);          // softmax denom cancels in renorm
    float inv = 1.f / (1.f + p2);
    int p0 = atomicAdd(&cnt[i1], 1); if (p0 >= CAP) p0 = CAP - 1;
    int p1 = atomicAdd(&cnt[i2], 1); if (p1 >= CAP) p1 = CAP - 1;
    int s0 = i1 * CAP + p0, s1 = i2 * CAP + p1;
    toks[s0] = n; toks[s1] = n;
    slot_of[n * 2 + 0] = s0; slot_of[n * 2 + 1] = s1;
    wtk[n * 2 + 0] = inv; wtk[n * 2 + 1] = p2 * inv;
    sgate[n] = 1.f / (1.f + __expf(-gd));
  }
}

// ---------------- merged gate_up + SwiGLU (shared [0,1408), expert [1408,5504)) ---------------
__global__ __launch_bounds__(256, 4) void gateup_kernel(
    const float* __restrict__ X, const float* __restrict__ WGU,
    const float* __restrict__ SWG, const float* __restrict__ SWU,
    ushort_t* __restrict__ HX, ushort_t* __restrict__ HS,
    const int* __restrict__ toks, const int* __restrict__ CNT) {
  __shared__ __align__(16) ushort_t As[GBM][LDK];
  __shared__ __align__(16) ushort_t Bgs[BN][LDK];
  __shared__ __align__(16) ushort_t Bus[BN][LDK];
  const int K = DH, NT = K / BK;

  int bid = blockIdx.x;
  int t = threadIdx.x;
  int wave = t >> 6, lane = t & 63;
  int wm = wave & 1, wn = wave >> 1;
  int qd = lane >> 4, l16 = lane & 15;
  int sr = t >> 3, sc = (t & 7) * 8;

  f32x4 accg[2][2], accu[2][2];
  #pragma unroll
  for (int i = 0; i < 2; ++i)
    #pragma unroll
    for (int j = 0; j < 2; ++j) {
      accg[i][j] = (f32x4){0.f, 0.f, 0.f, 0.f};
      accu[i][j] = (f32x4){0.f, 0.f, 0.f, 0.f};
    }

  int m0, n0, M, base, is_exp;

  if (bid < 1408) {
    // ---------- shared path: fp32 sources, fused packed cvt ----------
    is_exp = 0; base = 0; M = N_TOK;
    n0 = (bid % 44) * BN; m0 = (bid / 44) * GBM;
    const float* arow[2];
    const float *bgrow[2], *burow[2];
    #pragma unroll
    for (int p = 0; p < 2; ++p)
      arow[p] = X + (size_t)(m0 + sr + 32 * p) * K + sc;
    #pragma unroll
    for (int p = 0; p < 2; ++p) {
      bgrow[p] = SWG + (size_t)(n0 + sr + 32 * p) * K + sc;
      burow[p] = SWU + (size_t)(n0 + sr + 32 * p) * K + sc;
    }
    uint4 ar[2], bgr[2], bur[2];
    #pragma unroll
    for (int p = 0; p < 2; ++p) { ar[p] = ld_cvt8(arow[p]); bgr[p] = ld_cvt8(bgrow[p]); bur[p] = ld_cvt8(burow[p]); }

    for (int kt = 0; kt < NT; ++kt) {
      #pragma unroll
      for (int p = 0; p < 2; ++p) {
        *(uint4*)&As[sr + 32 * p][sc] = ar[p];
        *(uint4*)&Bgs[sr + 32 * p][sc] = bgr[p];
        *(uint4*)&Bus[sr + 32 * p][sc] = bur[p];
      }
      __syncthreads();
      if (kt + 1 < NT) {
        int ko = (kt + 1) * BK;
        #pragma unroll
        for (int p = 0; p < 2; ++p) { ar[p] = ld_cvt8(arow[p] + ko); bgr[p] = ld_cvt8(bgrow[p] + ko); bur[p] = ld_cvt8(burow[p] + ko); }
      }
      #pragma unroll
      for (int ks = 0; ks < 2; ++ks) {
        int kk = ks * 32 + qd * 8;
        bf16x8 af[2], bgf[2], buf[2];
        #pragma unroll
        for (int i = 0; i < 2; ++i)
          af[i] = *(const bf16x8*)&As[wm * 32 + i * 16 + l16][kk];
        #pragma unroll
        for (int j = 0; j < 2; ++j) {
          bgf[j] = *(const bf16x8*)&Bgs[wn * 32 + j * 16 + l16][kk];
          buf[j] = *(const bf16x8*)&Bus[wn * 32 + j * 16 + l16][kk];
        }
        #pragma unroll
        for (int i = 0; i < 2; ++i)
          #pragma unroll
          for (int j = 0; j < 2; ++j) {
            accg[i][j] = __builtin_amdgcn_mfma_f32_16x16x32_bf16(af[i], bgf[j], accg[i][j], 0, 0, 0);
            accu[i][j] = __builtin_amdgcn_mfma_f32_16x16x32_bf16(af[i], buf[j], accu[i][j], 0, 0, 0);
          }
      }
      __syncthreads();
    }
  } else {
    // ---------- expert path: B = wgu[e] [1024 k][1024 n], gather-transpose staged ----------
    is_exp = 1;
    int b2 = bid - 1408;
    int e = b2 >> 8, rem = b2 & 255;
    n0 = (rem & 7) * BN; m0 = (rem >> 3) * GBM;
    base = e * CAP; M = CNT[e];
    if (m0 >= M) return;
    const float* W = WGU + (size_t)e * DH * (2 * FF);
    int tn = t & 63, tk = (t >> 6) * 16;

    const float* arow[2];
    #pragma unroll
    for (int p = 0; p < 2; ++p) {
      int m = m0 + sr + 32 * p;
      int mm = m < M ? m : (M - 1);
      arow[p] = X + (size_t)toks[base + mm] * K + sc;
    }
    const float* wkb = W + (size_t)tk * (2 * FF) + n0 + tn;

    uint4 ar[2];
    float bgr[16], bur[16];
    #pragma unroll
    for (int p = 0; p < 2; ++p) ar[p] = ld_cvt8(arow[p]);
    #pragma unroll
    for (int j = 0; j < 16; ++j) {
      bgr[j] = wkb[(size_t)j * (2 * FF)];
      bur[j] = wkb[(size_t)j * (2 * FF) + FF];
    }

    for (int kt = 0; kt < NT; ++kt) {
      #pragma unroll
      for (int p = 0; p < 2; ++p)
        *(uint4*)&As[sr + 32 * p][sc] = ar[p];
      {
        uint4 g0, g1, u0, u1;
        g0.x = cvtpk(bgr[0], bgr[1]);  g0.y = cvtpk(bgr[2], bgr[3]);
        g0.z = cvtpk(bgr[4], bgr[5]);  g0.w = cvtpk(bgr[6], bgr[7]);
        g1.x = cvtpk(bgr[8], bgr[9]);  g1.y = cvtpk(bgr[10], bgr[11]);
        g1.z = cvtpk(bgr[12], bgr[13]); g1.w = cvtpk(bgr[14], bgr[15]);
        u0.x = cvtpk(bur[0], bur[1]);  u0.y = cvtpk(bur[2], bur[3]);
        u0.z = cvtpk(bur[4], bur[5]);  u0.w = cvtpk(bur[6], bur[7]);
        u1.x = cvtpk(bur[8], bur[9]);  u1.y = cvtpk(bur[10], bur[11]);
        u1.z = cvtpk(bur[12], bur[13]); u1.w = cvtpk(bur[14], bur[15]);
        *(uint4*)&Bgs[tn][tk]     = g0;
        *(uint4*)&Bgs[tn][tk + 8] = g1;
        *(uint4*)&Bus[tn][tk]     = u0;
        *(uint4*)&Bus[tn][tk + 8] = u1;
      }
      __syncthreads();
      if (kt + 1 < NT) {
        int ko = (kt + 1) * BK;
        #pragma unroll
        for (int p = 0; p < 2; ++p) ar[p] = ld_cvt8(arow[p] + ko);
        const float* wk = wkb + (size_t)ko * (2 * FF);
        #pragma unroll
        for (int j = 0; j < 16; ++j) {
          bgr[j] = wk[(size_t)j * (2 * FF)];
          bur[j] = wk[(size_t)j * (2 * FF) + FF];
        }
      }
      #pragma unroll
      for (int ks = 0; ks < 2; ++ks) {
        int kk = ks * 32 + qd * 8;
        bf16x8 af[2], bgf[2], buf[2];
        #pragma unroll
        for (int i = 0; i < 2; ++i)
          af[i] = *(const bf16x8*)&As[wm * 32 + i * 16 + l16][kk];
        #pragma unroll
        for (int j = 0; j < 2; ++j) {
          bgf[j] = *(const bf16x8*)&Bgs[wn * 32 + j * 16 + l16][kk];
          buf[j] = *(const bf16x8*)&Bus[wn * 32 + j * 16 + l16][kk];
        }
        #pragma unroll
        for (int i = 0; i < 2; ++i)
          #pragma unroll
          for (int j = 0; j < 2; ++j) {
            accg[i][j] = __builtin_amdgcn_mfma_f32_16x16x32_bf16(af[i], bgf[j], accg[i][j], 0, 0, 0);
            accu[i][j] = __builtin_amdgcn_mfma_f32_16x16x32_bf16(af[i], buf[j], accu[i][j], 0, 0, 0);
          }
      }
      __syncthreads();
    }
  }

  // ---------- epilogue: SwiGLU -> LDS bounce -> coalesced uint4 stores ----------
  #pragma unroll
  for (int i = 0; i < 2; ++i)
    #pragma unroll
    for (int r = 0; r < 4; ++r) {
      int row = wm * 32 + i * 16 + qd * 4 + r;
      #pragma unroll
      for (int j = 0; j < 2; ++j) {
        float g = accg[i][j][r], u = accu[i][j][r];
        float h = g / (1.f + __expf(-g)) * u;   // silu(g)*u
        As[row][wn * 32 + j * 16 + l16] = f2bf(h);
      }
    }
  __syncthreads();
  if (is_exp) {
    #pragma unroll
    for (int p = 0; p < 2; ++p) {
      int m = m0 + sr + 32 * p;
      if (m < M)
        *(uint4*)(HX + (size_t)(base + m) * FF + n0 + sc) = *(uint4*)&As[sr + 32 * p][sc];
    }
  } else {
    #pragma unroll
    for (int p = 0; p < 2; ++p) {
      int m = m0 + sr + 32 * p;
      *(uint4*)(HS + (size_t)m * SFF + n0 + sc) = *(uint4*)&As[sr + 32 * p][sc];
    }
  }
}

// ---------------- merged down (shared [0,512), expert [512,8704)) ----------------
// r13/r14 config; split-K removed: shared NT=44, single SD output.
__global__ __launch_bounds__(256, 4) void down_kernel(
    const ushort_t* __restrict__ HX, const ushort_t* __restrict__ HS,
    const float* __restrict__ WDN, const float* __restrict__ SWD,
    ushort_t* __restrict__ SD, ushort_t* __restrict__ EXPO,
    const int* __restrict__ CNT) {
  __shared__ __align__(16) ushort_t As[DBM][LDK];
  __shared__ __align__(16) ushort_t Bs[BN][LDK];

  int bid = blockIdx.x;
  int t = threadIdx.x;
  int wave = t >> 6, lane = t & 63;
  int wm = wave & 1, wn = wave >> 1;
  int qd = lane >> 4, l16 = lane & 15;
  int sr = t >> 3, sc = (t & 7) * 8;

  f32x4 c[2][2];
  #pragma unroll
  for (int i = 0; i < 2; ++i)
    #pragma unroll
    for (int j = 0; j < 2; ++j) c[i][j] = (f32x4){0.f, 0.f, 0.f, 0.f};

  int m0, n0, M, base_row;
  ushort_t* outp;

  if (bid < 512) {
    // ---------- shared path: A bf16 (HS), B fp32 (SWD) packed cvt, full K=2816 ----------
    m0 = (bid >> 4) * DBM; n0 = (bid & 15) * BN;
    M = N_TOK; base_row = 0;
    const int NT = SFF / BK;   // 44
    outp = SD;

    const ushort_t* arow[2];
    const float* brow[2];
    #pragma unroll
    for (int p = 0; p < 2; ++p) {
      arow[p] = HS + (size_t)(m0 + sr + 32 * p) * SFF + sc;
      brow[p] = SWD + (size_t)(n0 + sr + 32 * p) * SFF + sc;
    }

    uint4 ar[2], br[2];
    #pragma unroll
    for (int p = 0; p < 2; ++p) { ar[p] = *(const uint4*)(arow[p]); br[p] = ld_cvt8(brow[p]); }

    for (int kt = 0; kt < NT; ++kt) {
      #pragma unroll
      for (int p = 0; p < 2; ++p) {
        *(uint4*)&As[sr + 32 * p][sc] = ar[p];
        *(uint4*)&Bs[sr + 32 * p][sc] = br[p];
      }
      __syncthreads();
      if (kt + 1 < NT) {
        int ko = (kt + 1) * BK;
        #pragma unroll
        for (int p = 0; p < 2; ++p) { ar[p] = *(const uint4*)(arow[p] + ko); br[p] = ld_cvt8(brow[p] + ko); }
      }
      #pragma unroll
      for (int ks = 0; ks < 2; ++ks) {
        int kk = ks * 32 + qd * 8;
        bf16x8 af[2], bf[2];
        #pragma unroll
        for (int i = 0; i < 2; ++i)
          af[i] = *(const bf16x8*)&As[wm * 32 + i * 16 + l16][kk];
        #pragma unroll
        for (int j = 0; j < 2; ++j)
          bf[j] = *(const bf16x8*)&Bs[wn * 32 + j * 16 + l16][kk];
        #pragma unroll
        for (int i = 0; i < 2; ++i)
          #pragma unroll
          for (int j = 0; j < 2; ++j)
            c[i][j] = __builtin_amdgcn_mfma_f32_16x16x32_bf16(af[i], bf[j], c[i][j], 0, 0, 0);
      }
      __syncthreads();
    }
  } else {
    // ---------- expert path: A bf16 (HX), B = wdn[e] [512 k][1024 n] fp32 gather-transpose ----
    int b2 = bid - 512;
    int e = b2 >> 9, rem = b2 & 511;
    m0 = (rem >> 4) * DBM; n0 = (rem & 15) * BN;
    int base = e * CAP;
    M = CNT[e];
    if (m0 >= M) return;
    base_row = base;
    const int NT = FF / BK;   // 8
    const float* W = WDN + (size_t)e * FF * DH;
    const ushort_t* A = HX + (size_t)base * FF;
    int tn = t & 63, tk = (t >> 6) * 16;
    outp = EXPO;

    const ushort_t* arow[2];
    #pragma unroll
    for (int p = 0; p < 2; ++p) {
      int m = m0 + sr + 32 * p;
      int mm = m < M ? m : (M - 1);
      arow[p] = A + (size_t)mm * FF + sc;
    }
    const float* wkb = W + (size_t)tk * DH + n0 + tn;

    uint4 ar[2];
    float br[16];
    #pragma unroll
    for (int p = 0; p < 2; ++p) ar[p] = *(const uint4*)(arow[p]);
    #pragma unroll
    for (int j = 0; j < 16; ++j) br[j] = wkb[(size_t)j * DH];

    for (int kt = 0; kt < NT; ++kt) {
      #pragma unroll
      for (int p = 0; p < 2; ++p)
        *(uint4*)&As[sr + 32 * p][sc] = ar[p];
      {
        uint4 b0, b1;
        b0.x = cvtpk(br[0], br[1]);   b0.y = cvtpk(br[2], br[3]);
        b0.z = cvtpk(br[4], br[5]);   b0.w = cvtpk(br[6], br[7]);
        b1.x = cvtpk(br[8], br[9]);   b1.y = cvtpk(br[10], br[11]);
        b1.z = cvtpk(br[12], br[13]); b1.w = cvtpk(br[14], br[15]);
        *(uint4*)&Bs[tn][tk]     = b0;
        *(uint4*)&Bs[tn][tk + 8] = b1;
      }
      __syncthreads();
      if (kt + 1 < NT) {
        int ko = (kt + 1) * BK;
        #pragma unroll
        for (int p = 0; p < 2; ++p) ar[p] = *(const uint4*)(arow[p] + ko);
        const float* wk = wkb + (size_t)ko * DH;
        #pragma unroll
        for (int j = 0; j < 16; ++j) br[j] = wk[(size_t)j * DH];
      }
      #pragma unroll
      for (int ks = 0; ks < 2; ++ks) {
        int kk = ks * 32 + qd * 8;
        bf16x8 af[2], bf[2];
        #pragma unroll
        for (int i = 0; i < 2; ++i)
          af[i] = *(const bf16x8*)&As[wm * 32 + i * 16 + l16][kk];
        #pragma unroll
        for (int j = 0; j < 2; ++j)
          bf[j] = *(const bf16x8*)&Bs[wn * 32 + j * 16 + l16][kk];
        #pragma unroll
        for (int i = 0; i < 2; ++i)
          #pragma unroll
          for (int j = 0; j < 2; ++j)
            c[i][j] = __builtin_amdgcn_mfma_f32_16x16x32_bf16(af[i], bf[j], c[i][j], 0, 0, 0);
      }
      __syncthreads();
    }
  }

  // ---------- epilogue: LDS bounce -> coalesced uint4 stores (bf16 out) ----------
  #pragma unroll
  for (int i = 0; i < 2; ++i)
    #pragma unroll
    for (int r = 0; r < 4; ++r) {
      int row = wm * 32 + i * 16 + qd * 4 + r;
      #pragma unroll
      for (int j = 0; j < 2; ++j)
        As[row][wn * 32 + j * 16 + l16] = f2bf(c[i][j][r]);
    }
  __syncthreads();
  #pragma unroll
  for (int p = 0; p < 2; ++p) {
    int m = m0 + sr + 32 * p;
    if (m < M)
      *(uint4*)(outp + (size_t)(base_row + m) * DH + n0 + sc) = *(uint4*)&As[sr + 32 * p][sc];
  }
}

// ---------------- combine: out = sg*sd + w0*expo[s0] + w1*expo[s1] ----------------
__global__ void combine_kernel(const ushort_t* __restrict__ SD,
                               const ushort_t* __restrict__ EXPO,
                               const float* __restrict__ sgate, const float* __restrict__ wtk,
                               const int* __restrict__ slot_of, float* __restrict__ out) {
  int n = blockIdx.x, t = threadIdx.x;
  float sg = sgate[n];
  float w0 = wtk[n * 2 + 0], w1 = wtk[n * 2 + 1];
  int s0 = slot_of[n * 2 + 0], s1 = slot_of[n * 2 + 1];
  int col = t * 4;
  ushort4 d0 = *(const ushort4*)(SD + (size_t)n * DH + col);
  ushort4 a  = *(const ushort4*)(EXPO + (size_t)s0 * DH + col);
  ushort4 b  = *(const ushort4*)(EXPO + (size_t)s1 * DH + col);
  float4 o;
  o.x = sg * bf2f(d0.x) + w0 * bf2f(a.x) + w1 * bf2f(b.x);
  o.y = sg * bf2f(d0.y) + w0 * bf2f(a.y) + w1 * bf2f(b.y);
  o.z = sg * bf2f(d0.z) + w0 * bf2f(a.z) + w1 * bf2f(b.z);
  o.w = sg * bf2f(d0.w) + w0 * bf2f(a.w) + w1 * bf2f(b.w);
  *(float4*)(out + (size_t)n * DH + col) = o;
}

// ---------------- launcher ----------------
extern "C" void kernel_launch(void* const* d_in, const int* in_sizes, int n_in,
                              void* d_out, int out_size, void* d_ws, size_t ws_size,
                              hipStream_t stream) {
  const float* x    = (const float*)d_in[0];   // [2048,1024]
  const float* gw   = (const float*)d_in[1];   // [16,1024]
  const float* wgu  = (const float*)d_in[2];   // [16,1024,1024] (k-major)
  const float* wdn  = (const float*)d_in[3];   // [16,512,1024]  (k-major)
  const float* swg  = (const float*)d_in[4];   // [2816,1024] NT
  const float* swu  = (const float*)d_in[5];   // [2816,1024] NT
  const float* swd  = (const float*)d_in[6];   // [1024,2816] NT
  const float* sgw  = (const float*)d_in[7];   // [1,1024]
  float* out = (float*)d_out;

  char* ws = (char*)d_ws;
  constexpr size_t OFF_HS   = 0;                                        // 11,534,336
  constexpr size_t OFF_HX   = OFF_HS   + (size_t)N_TOK * SFF * 2;       // +16,777,216
  constexpr size_t OFF_SD   = OFF_HX   + (size_t)NE * CAP * FF * 2;     // +4,194,304
  constexpr size_t OFF_EXPO = OFF_SD   + (size_t)N_TOK * DH * 2;        // +33,554,432
  constexpr size_t OFF_TOK  = OFF_EXPO + (size_t)NE * CAP * DH * 2;     // +65,536
  constexpr size_t OFF_SLOT = OFF_TOK  + (size_t)NE * CAP * 4;
  constexpr size_t OFF_WTK  = OFF_SLOT + 4096 * 4;
  constexpr size_t OFF_SG   = OFF_WTK  + 4096 * 4;
  constexpr size_t OFF_CNT  = OFF_SG   + 2048 * 4;                      // end ~66.2 MB

  ushort_t* hs    = (ushort_t*)(ws + OFF_HS);
  ushort_t* hx    = (ushort_t*)(ws + OFF_HX);
  ushort_t* sd    = (ushort_t*)(ws + OFF_SD);
  ushort_t* expo  = (ushort_t*)(ws + OFF_EXPO);
  int*      toks  = (int*)(ws + OFF_TOK);
  int*      slot_of = (int*)(ws + OFF_SLOT);
  float*    wtk   = (float*)(ws + OFF_WTK);
  float*    sgate = (float*)(ws + OFF_SG);
  int*      cnt   = (int*)(ws + OFF_CNT);

  hipMemsetAsync(cnt, 0, NE * sizeof(int), stream);
  router_kernel<<<N_TOK / 4, 256, 0, stream>>>(x, gw, sgw, toks, slot_of, wtk, sgate, cnt);
  // gateup: shared 32m*44n = 1408, expert 16e*32m*8n = 4096 (CAP/GBM = 16... 32 m-tiles cover CAP=1024? 1024/64=16)
  gateup_kernel<<<1408 + 4096, 256, 0, stream>>>(x, wgu, swg, swu, hx, hs, toks, cnt);
  // down: shared 32m*16n = 512, expert 16e*32m*16n = 8192
  down_kernel<<<512 + 8192, 256, 0, stream>>>(hx, hs, wdn, swd, sd, expo, cnt);
  combine_kernel<<<N_TOK, 256, 0, stream>>>(sd, expo, sgate, wtk, slot_of, out);
}

// Round 16
// 376.889 us; speedup vs baseline: 1.1142x; 1.1142x over previous
//
#include <hip/hip_runtime.h>
#include <hip/hip_bf16.h>

typedef unsigned short ushort_t;
typedef __bf16 bf16x8 __attribute__((ext_vector_type(8)));
typedef float f32x4 __attribute__((ext_vector_type(4)));

#define N_TOK 2048
#define DH    1024
#define FF    512
#define SFF   2816
#define NE    16

#define GBM 64   // gateup M-tile (r8 verified clean)
#define DBM 64   // down M-tile (r13 verified clean at (256,4))
#define BN 64
#define BK 64
#define LDK 72   // 64 + 8 pad (ushorts)

// manual RNE bf16 convert (scalar fallback)
__device__ __forceinline__ ushort_t f2bf(float f) {
  unsigned int x = __float_as_uint(f);
  unsigned int lsb = (x >> 16) & 1u;
  x += 0x7fffu + lsb;            // RNE; finite inputs
  return (ushort_t)(x >> 16);
}
__device__ __forceinline__ float bf2f(ushort_t u) {
  union { unsigned int i; float f; } v; v.i = ((unsigned int)u) << 16; return v.f;
}
// packed HW convert: 2 fp32 -> 2 bf16 (RNE), 1 VALU op. No builtin on gfx950 (m240) -> asm.
__device__ __forceinline__ unsigned int cvtpk(float lo, float hi) {
  unsigned int r;
  asm("v_cvt_pk_bf16_f32 %0, %1, %2" : "=v"(r) : "v"(lo), "v"(hi));
  return r;
}
__device__ __forceinline__ uint4 cvt8v(const float4 a, const float4 b) {
  uint4 v;
  v.x = cvtpk(a.x, a.y); v.y = cvtpk(a.z, a.w);
  v.z = cvtpk(b.x, b.y); v.w = cvtpk(b.z, b.w);
  return v;
}
__device__ __forceinline__ uint4 ld_cvt8(const float* __restrict__ p) {
  float4 a = *(const float4*)p;
  float4 b = *(const float4*)(p + 4);
  return cvt8v(a, b);
}

// ---------------- router (fp32, float4-vectorized): logits, top-2, renorm, sigmoid gate ------
__global__ void router_kernel(const float* __restrict__ X, const float* __restrict__ GW,
                              const float* __restrict__ SGW,
                              int* __restrict__ sel, float* __restrict__ wtk,
                              float* __restrict__ sgate) {
  int wave = threadIdx.x >> 6, lane = threadIdx.x & 63;
  int n = blockIdx.x * 4 + wave;
  const float* x = X + (size_t)n * DH;
  int e = lane & 15, s = lane >> 4;
  const float* gw = GW + (size_t)e * DH;
  float lg = 0.f;
  #pragma unroll
  for (int i = 0; i < 64; ++i) {
    int d = s * 256 + i * 4;
    float4 xv = *(const float4*)(x + d);
    float4 gv = *(const float4*)(gw + d);
    lg += xv.x * gv.x + xv.y * gv.y + xv.z * gv.z + xv.w * gv.w;
  }
  lg += __shfl_down(lg, 32);
  lg += __shfl_down(lg, 16);          // lanes 0..15 hold logits[e]

  float gd = 0.f;
  #pragma unroll
  for (int i = 0; i < 4; ++i) {
    int d = lane * 16 + i * 4;
    float4 xv = *(const float4*)(x + d);
    float4 gv = *(const float4*)(SGW + d);
    gd += xv.x * gv.x + xv.y * gv.y + xv.z * gv.z + xv.w * gv.w;
  }
  #pragma unroll
  for (int off = 32; off >= 1; off >>= 1) gd += __shfl_down(gd, off);

  float l[16];
  #pragma unroll
  for (int i = 0; i < 16; ++i) l[i] = __shfl(lg, i);

  if (lane == 0) {
    int i1 = 0; float v1 = l[0];
    #pragma unroll
    for (int i = 1; i < 16; ++i) if (l[i] > v1) { v1 = l[i]; i1 = i; }
    int i2 = -1; float v2 = -1e30f;
    #pragma unroll
    for (int i = 0; i < 16; ++i) { if (i == i1) continue; if (l[i] > v2) { v2 = l[i]; i2 = i; } }
    float p2 = __expf(v2 - v1);          // softmax denom cancels in renorm
    float inv = 1.f / (1.f + p2);
    sel[n * 2 + 0] = i1; sel[n * 2 + 1] = i2;
    wtk[n * 2 + 0] = inv; wtk[n * 2 + 1] = p2 * inv;
    sgate[n] = 1.f / (1.f + __expf(-gd));
  }
}

// ---------------- single-block scatter (LDS atomics — faster than device-scope, r15 lesson) --
__global__ void scatter_kernel(const int* __restrict__ sel,
                               int* __restrict__ toks, int* __restrict__ slot_of,
                               int* __restrict__ offs) {
  __shared__ int cnt[NE], bas[NE];
  int t = threadIdx.x;
  if (t < NE) cnt[t] = 0;
  __syncthreads();
  for (int i = t; i < N_TOK * 2; i += 256) atomicAdd(&cnt[sel[i]], 1);
  __syncthreads();
  if (t == 0) {
    int s = 0;
    for (int e = 0; e < NE; ++e) { bas[e] = s; offs[e] = s; s += cnt[e]; }
    offs[NE] = s;
  }
  __syncthreads();
  if (t < NE) cnt[t] = 0;
  __syncthreads();
  for (int i = t; i < N_TOK * 2; i += 256) {
    int e = sel[i];
    int p = atomicAdd(&cnt[e], 1);
    int slot = bas[e] + p;
    toks[slot] = i >> 1;
    slot_of[i] = slot;
  }
}

// ---------------- merged gate_up + SwiGLU (shared [0,1408), expert [1408,5504)) ---------------
// r8/r13 config; in-loop cvt via v_cvt_pk_bf16_f32 (4 ops/8 elems vs ~40).
__global__ __launch_bounds__(256, 4) void gateup_kernel(
    const float* __restrict__ X, const float* __restrict__ WGU,
    const float* __restrict__ SWG, const float* __restrict__ SWU,
    ushort_t* __restrict__ HX, ushort_t* __restrict__ HS,
    const int* __restrict__ toks, const int* __restrict__ offs) {
  __shared__ __align__(16) ushort_t As[GBM][LDK];
  __shared__ __align__(16) ushort_t Bgs[BN][LDK];
  __shared__ __align__(16) ushort_t Bus[BN][LDK];
  const int K = DH, NT = K / BK;

  int bid = blockIdx.x;
  int t = threadIdx.x;
  int wave = t >> 6, lane = t & 63;
  int wm = wave & 1, wn = wave >> 1;
  int qd = lane >> 4, l16 = lane & 15;
  int sr = t >> 3, sc = (t & 7) * 8;

  f32x4 accg[2][2], accu[2][2];
  #pragma unroll
  for (int i = 0; i < 2; ++i)
    #pragma unroll
    for (int j = 0; j < 2; ++j) {
      accg[i][j] = (f32x4){0.f, 0.f, 0.f, 0.f};
      accu[i][j] = (f32x4){0.f, 0.f, 0.f, 0.f};
    }

  int m0, n0, M, base, is_exp;

  if (bid < 1408) {
    // ---------- shared path: fp32 sources, fused packed cvt ----------
    is_exp = 0; base = 0; M = N_TOK;
    n0 = (bid % 44) * BN; m0 = (bid / 44) * GBM;
    const float* arow[2];
    const float *bgrow[2], *burow[2];
    #pragma unroll
    for (int p = 0; p < 2; ++p)
      arow[p] = X + (size_t)(m0 + sr + 32 * p) * K + sc;
    #pragma unroll
    for (int p = 0; p < 2; ++p) {
      bgrow[p] = SWG + (size_t)(n0 + sr + 32 * p) * K + sc;
      burow[p] = SWU + (size_t)(n0 + sr + 32 * p) * K + sc;
    }
    uint4 ar[2], bgr[2], bur[2];
    #pragma unroll
    for (int p = 0; p < 2; ++p) { ar[p] = ld_cvt8(arow[p]); bgr[p] = ld_cvt8(bgrow[p]); bur[p] = ld_cvt8(burow[p]); }

    for (int kt = 0; kt < NT; ++kt) {
      #pragma unroll
      for (int p = 0; p < 2; ++p) {
        *(uint4*)&As[sr + 32 * p][sc] = ar[p];
        *(uint4*)&Bgs[sr + 32 * p][sc] = bgr[p];
        *(uint4*)&Bus[sr + 32 * p][sc] = bur[p];
      }
      __syncthreads();
      if (kt + 1 < NT) {
        int ko = (kt + 1) * BK;
        #pragma unroll
        for (int p = 0; p < 2; ++p) { ar[p] = ld_cvt8(arow[p] + ko); bgr[p] = ld_cvt8(bgrow[p] + ko); bur[p] = ld_cvt8(burow[p] + ko); }
      }
      #pragma unroll
      for (int ks = 0; ks < 2; ++ks) {
        int kk = ks * 32 + qd * 8;
        bf16x8 af[2], bgf[2], buf[2];
        #pragma unroll
        for (int i = 0; i < 2; ++i)
          af[i] = *(const bf16x8*)&As[wm * 32 + i * 16 + l16][kk];
        #pragma unroll
        for (int j = 0; j < 2; ++j) {
          bgf[j] = *(const bf16x8*)&Bgs[wn * 32 + j * 16 + l16][kk];
          buf[j] = *(const bf16x8*)&Bus[wn * 32 + j * 16 + l16][kk];
        }
        #pragma unroll
        for (int i = 0; i < 2; ++i)
          #pragma unroll
          for (int j = 0; j < 2; ++j) {
            accg[i][j] = __builtin_amdgcn_mfma_f32_16x16x32_bf16(af[i], bgf[j], accg[i][j], 0, 0, 0);
            accu[i][j] = __builtin_amdgcn_mfma_f32_16x16x32_bf16(af[i], buf[j], accu[i][j], 0, 0, 0);
          }
      }
      __syncthreads();
    }
  } else {
    // ---------- expert path: B = wgu[e] [1024 k][1024 n], gather-transpose staged ----------
    is_exp = 1;
    int b2 = bid - 1408;
    int e = b2 >> 8, rem = b2 & 255;
    n0 = (rem & 7) * BN; m0 = (rem >> 3) * GBM;
    base = offs[e]; M = offs[e + 1] - base;
    if (m0 >= M) return;
    const float* W = WGU + (size_t)e * DH * (2 * FF);
    int tn = t & 63, tk = (t >> 6) * 16;

    const float* arow[2];
    #pragma unroll
    for (int p = 0; p < 2; ++p) {
      int m = m0 + sr + 32 * p;
      int mm = m < M ? m : (M - 1);
      arow[p] = X + (size_t)toks[base + mm] * K + sc;
    }
    const float* wkb = W + (size_t)tk * (2 * FF) + n0 + tn;

    uint4 ar[2];
    float bgr[16], bur[16];
    #pragma unroll
    for (int p = 0; p < 2; ++p) ar[p] = ld_cvt8(arow[p]);
    #pragma unroll
    for (int j = 0; j < 16; ++j) {
      bgr[j] = wkb[(size_t)j * (2 * FF)];
      bur[j] = wkb[(size_t)j * (2 * FF) + FF];
    }

    for (int kt = 0; kt < NT; ++kt) {
      #pragma unroll
      for (int p = 0; p < 2; ++p)
        *(uint4*)&As[sr + 32 * p][sc] = ar[p];
      {
        uint4 g0, g1, u0, u1;
        g0.x = cvtpk(bgr[0], bgr[1]);  g0.y = cvtpk(bgr[2], bgr[3]);
        g0.z = cvtpk(bgr[4], bgr[5]);  g0.w = cvtpk(bgr[6], bgr[7]);
        g1.x = cvtpk(bgr[8], bgr[9]);  g1.y = cvtpk(bgr[10], bgr[11]);
        g1.z = cvtpk(bgr[12], bgr[13]); g1.w = cvtpk(bgr[14], bgr[15]);
        u0.x = cvtpk(bur[0], bur[1]);  u0.y = cvtpk(bur[2], bur[3]);
        u0.z = cvtpk(bur[4], bur[5]);  u0.w = cvtpk(bur[6], bur[7]);
        u1.x = cvtpk(bur[8], bur[9]);  u1.y = cvtpk(bur[10], bur[11]);
        u1.z = cvtpk(bur[12], bur[13]); u1.w = cvtpk(bur[14], bur[15]);
        *(uint4*)&Bgs[tn][tk]     = g0;
        *(uint4*)&Bgs[tn][tk + 8] = g1;
        *(uint4*)&Bus[tn][tk]     = u0;
        *(uint4*)&Bus[tn][tk + 8] = u1;
      }
      __syncthreads();
      if (kt + 1 < NT) {
        int ko = (kt + 1) * BK;
        #pragma unroll
        for (int p = 0; p < 2; ++p) ar[p] = ld_cvt8(arow[p] + ko);
        const float* wk = wkb + (size_t)ko * (2 * FF);
        #pragma unroll
        for (int j = 0; j < 16; ++j) {
          bgr[j] = wk[(size_t)j * (2 * FF)];
          bur[j] = wk[(size_t)j * (2 * FF) + FF];
        }
      }
      #pragma unroll
      for (int ks = 0; ks < 2; ++ks) {
        int kk = ks * 32 + qd * 8;
        bf16x8 af[2], bgf[2], buf[2];
        #pragma unroll
        for (int i = 0; i < 2; ++i)
          af[i] = *(const bf16x8*)&As[wm * 32 + i * 16 + l16][kk];
        #pragma unroll
        for (int j = 0; j < 2; ++j) {
          bgf[j] = *(const bf16x8*)&Bgs[wn * 32 + j * 16 + l16][kk];
          buf[j] = *(const bf16x8*)&Bus[wn * 32 + j * 16 + l16][kk];
        }
        #pragma unroll
        for (int i = 0; i < 2; ++i)
          #pragma unroll
          for (int j = 0; j < 2; ++j) {
            accg[i][j] = __builtin_amdgcn_mfma_f32_16x16x32_bf16(af[i], bgf[j], accg[i][j], 0, 0, 0);
            accu[i][j] = __builtin_amdgcn_mfma_f32_16x16x32_bf16(af[i], buf[j], accu[i][j], 0, 0, 0);
          }
      }
      __syncthreads();
    }
  }

  // ---------- epilogue: SwiGLU -> LDS bounce -> coalesced uint4 stores ----------
  #pragma unroll
  for (int i = 0; i < 2; ++i)
    #pragma unroll
    for (int r = 0; r < 4; ++r) {
      int row = wm * 32 + i * 16 + qd * 4 + r;
      #pragma unroll
      for (int j = 0; j < 2; ++j) {
        float g = accg[i][j][r], u = accu[i][j][r];
        float h = g / (1.f + __expf(-g)) * u;   // silu(g)*u
        As[row][wn * 32 + j * 16 + l16] = f2bf(h);
      }
    }
  __syncthreads();
  if (is_exp) {
    #pragma unroll
    for (int p = 0; p < 2; ++p) {
      int m = m0 + sr + 32 * p;
      if (m < M)
        *(uint4*)(HX + (size_t)(base + m) * FF + n0 + sc) = *(uint4*)&As[sr + 32 * p][sc];
    }
  } else {
    #pragma unroll
    for (int p = 0; p < 2; ++p) {
      int m = m0 + sr + 32 * p;
      *(uint4*)(HS + (size_t)m * SFF + n0 + sc) = *(uint4*)&As[sr + 32 * p][sc];
    }
  }
}

// ---------------- merged down (shared [0,1024), expert [1024,9216)) ----------------
// r13 config: DBM=64, (256,4). Packed cvt for B staging.
__global__ __launch_bounds__(256, 4) void down_kernel(
    const ushort_t* __restrict__ HX, const ushort_t* __restrict__ HS,
    const float* __restrict__ WDN, const float* __restrict__ SWD,
    ushort_t* __restrict__ SD0, ushort_t* __restrict__ SD1,
    ushort_t* __restrict__ EXPO, const int* __restrict__ offs) {
  __shared__ __align__(16) ushort_t As[DBM][LDK];
  __shared__ __align__(16) ushort_t Bs[BN][LDK];

  int bid = blockIdx.x;
  int t = threadIdx.x;
  int wave = t >> 6, lane = t & 63;
  int wm = wave & 1, wn = wave >> 1;
  int qd = lane >> 4, l16 = lane & 15;
  int sr = t >> 3, sc = (t & 7) * 8;

  f32x4 c[2][2];
  #pragma unroll
  for (int i = 0; i < 2; ++i)
    #pragma unroll
    for (int j = 0; j < 2; ++j) c[i][j] = (f32x4){0.f, 0.f, 0.f, 0.f};

  int m0, n0, M, base_row;
  ushort_t* outp;

  if (bid < 1024) {
    // ---------- shared path: A bf16 (HS), B fp32 (SWD) packed cvt, K chunk 1408 ----------
    int kz = bid >> 9, rem = bid & 511;
    m0 = (rem >> 4) * DBM; n0 = (rem & 15) * BN;
    M = N_TOK; base_row = 0;
    const int KC = SFF / 2, NT = KC / BK;   // 22
    int kb = kz * KC;
    outp = kz ? SD1 : SD0;

    const ushort_t* arow[2];
    const float* brow[2];
    #pragma unroll
    for (int p = 0; p < 2; ++p) {
      arow[p] = HS + (size_t)(m0 + sr + 32 * p) * SFF + kb + sc;
      brow[p] = SWD + (size_t)(n0 + sr + 32 * p) * SFF + kb + sc;
    }

    uint4 ar[2], br[2];
    #pragma unroll
    for (int p = 0; p < 2; ++p) { ar[p] = *(const uint4*)(arow[p]); br[p] = ld_cvt8(brow[p]); }

    for (int kt = 0; kt < NT; ++kt) {
      #pragma unroll
      for (int p = 0; p < 2; ++p) {
        *(uint4*)&As[sr + 32 * p][sc] = ar[p];
        *(uint4*)&Bs[sr + 32 * p][sc] = br[p];
      }
      __syncthreads();
      if (kt + 1 < NT) {
        int ko = (kt + 1) * BK;
        #pragma unroll
        for (int p = 0; p < 2; ++p) { ar[p] = *(const uint4*)(arow[p] + ko); br[p] = ld_cvt8(brow[p] + ko); }
      }
      #pragma unroll
      for (int ks = 0; ks < 2; ++ks) {
        int kk = ks * 32 + qd * 8;
        bf16x8 af[2], bf[2];
        #pragma unroll
        for (int i = 0; i < 2; ++i)
          af[i] = *(const bf16x8*)&As[wm * 32 + i * 16 + l16][kk];
        #pragma unroll
        for (int j = 0; j < 2; ++j)
          bf[j] = *(const bf16x8*)&Bs[wn * 32 + j * 16 + l16][kk];
        #pragma unroll
        for (int i = 0; i < 2; ++i)
          #pragma unroll
          for (int j = 0; j < 2; ++j)
            c[i][j] = __builtin_amdgcn_mfma_f32_16x16x32_bf16(af[i], bf[j], c[i][j], 0, 0, 0);
      }
      __syncthreads();
    }
  } else {
    // ---------- expert path: A bf16 (HX), B = wdn[e] [512 k][1024 n] fp32 gather-transpose ----
    int b2 = bid - 1024;
    int e = b2 >> 9, rem = b2 & 511;
    m0 = (rem >> 4) * DBM; n0 = (rem & 15) * BN;
    int base = offs[e];
    M = offs[e + 1] - base;
    if (m0 >= M) return;
    base_row = base;
    const int NT = FF / BK;   // 8
    const float* W = WDN + (size_t)e * FF * DH;
    const ushort_t* A = HX + (size_t)base * FF;
    int tn = t & 63, tk = (t >> 6) * 16;
    outp = EXPO;

    const ushort_t* arow[2];
    #pragma unroll
    for (int p = 0; p < 2; ++p) {
      int m = m0 + sr + 32 * p;
      int mm = m < M ? m : (M - 1);
      arow[p] = A + (size_t)mm * FF + sc;
    }
    const float* wkb = W + (size_t)tk * DH + n0 + tn;

    uint4 ar[2];
    float br[16];
    #pragma unroll
    for (int p = 0; p < 2; ++p) ar[p] = *(const uint4*)(arow[p]);
    #pragma unroll
    for (int j = 0; j < 16; ++j) br[j] = wkb[(size_t)j * DH];

    for (int kt = 0; kt < NT; ++kt) {
      #pragma unroll
      for (int p = 0; p < 2; ++p)
        *(uint4*)&As[sr + 32 * p][sc] = ar[p];
      {
        uint4 b0, b1;
        b0.x = cvtpk(br[0], br[1]);   b0.y = cvtpk(br[2], br[3]);
        b0.z = cvtpk(br[4], br[5]);   b0.w = cvtpk(br[6], br[7]);
        b1.x = cvtpk(br[8], br[9]);   b1.y = cvtpk(br[10], br[11]);
        b1.z = cvtpk(br[12], br[13]); b1.w = cvtpk(br[14], br[15]);
        *(uint4*)&Bs[tn][tk]     = b0;
        *(uint4*)&Bs[tn][tk + 8] = b1;
      }
      __syncthreads();
      if (kt + 1 < NT) {
        int ko = (kt + 1) * BK;
        #pragma unroll
        for (int p = 0; p < 2; ++p) ar[p] = *(const uint4*)(arow[p] + ko);
        const float* wk = wkb + (size_t)ko * DH;
        #pragma unroll
        for (int j = 0; j < 16; ++j) br[j] = wk[(size_t)j * DH];
      }
      #pragma unroll
      for (int ks = 0; ks < 2; ++ks) {
        int kk = ks * 32 + qd * 8;
        bf16x8 af[2], bf[2];
        #pragma unroll
        for (int i = 0; i < 2; ++i)
          af[i] = *(const bf16x8*)&As[wm * 32 + i * 16 + l16][kk];
        #pragma unroll
        for (int j = 0; j < 2; ++j)
          bf[j] = *(const bf16x8*)&Bs[wn * 32 + j * 16 + l16][kk];
        #pragma unroll
        for (int i = 0; i < 2; ++i)
          #pragma unroll
          for (int j = 0; j < 2; ++j)
            c[i][j] = __builtin_amdgcn_mfma_f32_16x16x32_bf16(af[i], bf[j], c[i][j], 0, 0, 0);
      }
      __syncthreads();
    }
  }

  // ---------- epilogue: LDS bounce -> coalesced uint4 stores (bf16 out) ----------
  #pragma unroll
  for (int i = 0; i < 2; ++i)
    #pragma unroll
    for (int r = 0; r < 4; ++r) {
      int row = wm * 32 + i * 16 + qd * 4 + r;
      #pragma unroll
      for (int j = 0; j < 2; ++j)
        As[row][wn * 32 + j * 16 + l16] = f2bf(c[i][j][r]);
    }
  __syncthreads();
  #pragma unroll
  for (int p = 0; p < 2; ++p) {
    int m = m0 + sr + 32 * p;
    if (m < M)
      *(uint4*)(outp + (size_t)(base_row + m) * DH + n0 + sc) = *(uint4*)&As[sr + 32 * p][sc];
  }
}

// ---------------- combine: out = sg*(sd0+sd1) + w0*expo[s0] + w1*expo[s1] ----------------
__global__ void combine_kernel(const ushort_t* __restrict__ SD0, const ushort_t* __restrict__ SD1,
                               const ushort_t* __restrict__ EXPO,
                               const float* __restrict__ sgate, const float* __restrict__ wtk,
                               const int* __restrict__ slot_of, float* __restrict__ out) {
  int n = blockIdx.x, t = threadIdx.x;
  float sg = sgate[n];
  float w0 = wtk[n * 2 + 0], w1 = wtk[n * 2 + 1];
  int s0 = slot_of[n * 2 + 0], s1 = slot_of[n * 2 + 1];
  int col = t * 4;
  ushort4 d0 = *(const ushort4*)(SD0 + (size_t)n * DH + col);
  ushort4 d1 = *(const ushort4*)(SD1 + (size_t)n * DH + col);
  ushort4 a  = *(const ushort4*)(EXPO + (size_t)s0 * DH + col);
  ushort4 b  = *(const ushort4*)(EXPO + (size_t)s1 * DH + col);
  float4 o;
  o.x = sg * (bf2f(d0.x) + bf2f(d1.x)) + w0 * bf2f(a.x) + w1 * bf2f(b.x);
  o.y = sg * (bf2f(d0.y) + bf2f(d1.y)) + w0 * bf2f(a.y) + w1 * bf2f(b.y);
  o.z = sg * (bf2f(d0.z) + bf2f(d1.z)) + w0 * bf2f(a.z) + w1 * bf2f(b.z);
  o.w = sg * (bf2f(d0.w) + bf2f(d1.w)) + w0 * bf2f(a.w) + w1 * bf2f(b.w);
  *(float4*)(out + (size_t)n * DH + col) = o;
}

// ---------------- launcher ----------------
extern "C" void kernel_launch(void* const* d_in, const int* in_sizes, int n_in,
                              void* d_out, int out_size, void* d_ws, size_t ws_size,
                              hipStream_t stream) {
  const float* x    = (const float*)d_in[0];   // [2048,1024]
  const float* gw   = (const float*)d_in[1];   // [16,1024]
  const float* wgu  = (const float*)d_in[2];   // [16,1024,1024] (k-major)
  const float* wdn  = (const float*)d_in[3];   // [16,512,1024]  (k-major)
  const float* swg  = (const float*)d_in[4];   // [2816,1024] NT
  const float* swu  = (const float*)d_in[5];   // [2816,1024] NT
  const float* swd  = (const float*)d_in[6];   // [1024,2816] NT
  const float* sgw  = (const float*)d_in[7];   // [1,1024]
  float* out = (float*)d_out;

  char* ws = (char*)d_ws;
  constexpr size_t OFF_HS   = 0;                                        // 11,534,336
  constexpr size_t OFF_HX   = OFF_HS   + (size_t)N_TOK * SFF * 2;       // +4,194,304
  constexpr size_t OFF_SD0  = OFF_HX   + (size_t)4096 * FF * 2;         // +4,194,304
  constexpr size_t OFF_SD1  = OFF_SD0  + (size_t)N_TOK * DH * 2;        // +4,194,304
  constexpr size_t OFF_EXPO = OFF_SD1  + (size_t)N_TOK * DH * 2;        // +8,388,608
  constexpr size_t OFF_TOK  = OFF_EXPO + (size_t)4096 * DH * 2;
  constexpr size_t OFF_OFFS = OFF_TOK  + 4096 * 4;
  constexpr size_t OFF_SEL  = OFF_OFFS + 32 * 4;
  constexpr size_t OFF_WTK  = OFF_SEL  + 4096 * 4;
  constexpr size_t OFF_SG   = OFF_WTK  + 4096 * 4;
  constexpr size_t OFF_SLOT = OFF_SG   + 2048 * 4;                      // end ~32.6 MB

  ushort_t* hs    = (ushort_t*)(ws + OFF_HS);
  ushort_t* hx    = (ushort_t*)(ws + OFF_HX);
  ushort_t* sd0   = (ushort_t*)(ws + OFF_SD0);
  ushort_t* sd1   = (ushort_t*)(ws + OFF_SD1);
  ushort_t* expo  = (ushort_t*)(ws + OFF_EXPO);
  int*      toks  = (int*)(ws + OFF_TOK);
  int*      offs  = (int*)(ws + OFF_OFFS);
  int*      sel   = (int*)(ws + OFF_SEL);
  float*    wtk   = (float*)(ws + OFF_WTK);
  float*    sgate = (float*)(ws + OFF_SG);
  int*      slot_of = (int*)(ws + OFF_SLOT);

  router_kernel<<<N_TOK / 4, 256, 0, stream>>>(x, gw, sgw, sel, wtk, sgate);
  scatter_kernel<<<1, 256, 0, stream>>>(sel, toks, slot_of, offs);
  // gateup: shared 32m*44n = 1408, expert 16e*32m*8n = 4096
  gateup_kernel<<<1408 + 4096, 256, 0, stream>>>(x, wgu, swg, swu, hx, hs, toks, offs);
  // down: shared 2kz*32m*16n = 1024, expert 16e*32m*16n = 8192
  down_kernel<<<1024 + 8192, 256, 0, stream>>>(hx, hs, wdn, swd, sd0, sd1, expo, offs);
  combine_kernel<<<N_TOK, 256, 0, stream>>>(sd0, sd1, expo, sgate, wtk, slot_of, out);
}